// Round 3
// baseline (3643.885 us; speedup 1.0000x reference)
//
#include <hip/hip_runtime.h>
#include <hip/hip_cooperative_groups.h>
#include <cstdint>
#include <cstddef>

namespace cg = cooperative_groups;

#define NN   4096
#define LLC  50

__device__ __forceinline__ float bf2f(unsigned short u) {
    return __uint_as_float(((unsigned)u) << 16);
}
__device__ __forceinline__ unsigned short f2bf(float x) {
    unsigned b = __float_as_uint(x);
    return (unsigned short)((b + 0x7fffu + ((b >> 16) & 1u)) >> 16);
}

#if __has_builtin(__builtin_amdgcn_sdot4)
#define SDOT4(a, b, c) __builtin_amdgcn_sdot4((int)(a), (int)(b), (c), false)
#else
__device__ __forceinline__ int sdot4_sw(unsigned a, unsigned b, int c) {
    c += (int)(signed char)(a) * (int)(signed char)(b);
    c += (int)(signed char)(a >> 8) * (int)(signed char)(b >> 8);
    c += (int)(signed char)(a >> 16) * (int)(signed char)(b >> 16);
    c += (int)(signed char)(a >> 24) * (int)(signed char)(b >> 24);
    return c;
}
#define SDOT4(a, b, c) sdot4_sw((a), (b), (c))
#endif

// sum across 64 lanes via DPP (VALU pipe, rocPRIM pattern); total lands in lane 63
#define DPPADD(v, ctrl, rmask) \
    ((v) + __builtin_amdgcn_update_dpp(0, (v), (ctrl), (rmask), 0xf, true))
__device__ __forceinline__ int wred64(int v) {
    v = DPPADD(v, 0x111, 0xf);   // row_shr:1
    v = DPPADD(v, 0x112, 0xf);   // row_shr:2
    v = DPPADD(v, 0x114, 0xf);   // row_shr:4
    v = DPPADD(v, 0x118, 0xf);   // row_shr:8  -> lane15/31/47/63 hold row sums
    v = DPPADD(v, 0x142, 0xa);   // row_bcast15 -> lane31=r0+r1, lane63=r2+r3
    v = DPPADD(v, 0x143, 0xc);   // row_bcast31 -> lane63=total
    return v;
}

// ---- W_hh fp32 -> int8 (x8192), packed 4/dword -----------------------------
__global__ __launch_bounds__(256) void k_w8(const float* __restrict__ W,
                                            unsigned* __restrict__ out) {
    size_t i = (size_t)blockIdx.x * 256 + threadIdx.x;   // dword index
    float4 w = *(const float4*)(W + i * 4);
    int q0 = (int)rintf(fminf(fmaxf(w.x * 8192.f, -127.f), 127.f));
    int q1 = (int)rintf(fminf(fmaxf(w.y * 8192.f, -127.f), 127.f));
    int q2 = (int)rintf(fminf(fmaxf(w.z * 8192.f, -127.f), 127.f));
    int q3 = (int)rintf(fminf(fmaxf(w.w * 8192.f, -127.f), 127.f));
    out[i] = (q0 & 0xff) | ((q1 & 0xff) << 8) | ((q2 & 0xff) << 16) | ((q3 & 0xff) << 24);
}

// ---- filt1 = fea@W1, filt2 = fea@W2  -> bf16 [16384,128] -------------------
__global__ __launch_bounds__(128) void k_filt(const float* __restrict__ fea,
                                              const float* __restrict__ W1,
                                              const float* __restrict__ W2,
                                              unsigned short* __restrict__ f1,
                                              unsigned short* __restrict__ f2) {
    __shared__ float sfea[16][128];
    int t = threadIdx.x;
    int rb = blockIdx.x * 16;
    for (int r = 0; r < 16; ++r) sfea[r][t] = fea[(size_t)(rb + r) * 128 + t];
    __syncthreads();
    float a1[16], a2[16];
#pragma unroll
    for (int r = 0; r < 16; ++r) { a1[r] = 0.f; a2[r] = 0.f; }
    for (int c = 0; c < 128; c += 4) {
        float w10 = W1[(c + 0) * 128 + t], w11 = W1[(c + 1) * 128 + t];
        float w12 = W1[(c + 2) * 128 + t], w13 = W1[(c + 3) * 128 + t];
        float w20 = W2[(c + 0) * 128 + t], w21 = W2[(c + 1) * 128 + t];
        float w22 = W2[(c + 2) * 128 + t], w23 = W2[(c + 3) * 128 + t];
#pragma unroll
        for (int r = 0; r < 16; ++r) {
            float4 f = *(const float4*)&sfea[r][c];
            a1[r] += f.x * w10 + f.y * w11 + f.z * w12 + f.w * w13;
            a2[r] += f.x * w20 + f.y * w21 + f.z * w22 + f.w * w23;
        }
    }
#pragma unroll
    for (int r = 0; r < 16; ++r) {
        f1[(size_t)(rb + r) * 128 + t] = f2bf(a1[r]);
        f2[(size_t)(rb + r) * 128 + t] = f2bf(a2[r]);
    }
}

// ---- CSR build: LDS-privatized histogram -> scan -> packed scatter ----------
// segments s = m*4+b; m: 0=inv1, 1=phi1, 2=inv2, 3=phi2
__global__ __launch_bounds__(256) void k_hist(const int* __restrict__ i0, const int* __restrict__ i1,
                                              const int* __restrict__ i2, const int* __restrict__ i3,
                                              int* __restrict__ counts) {
    __shared__ int lc[4096];
    int t = threadIdx.x;
#pragma unroll
    for (int i = 0; i < 16; ++i) lc[t + i * 256] = 0;
    __syncthreads();
    unsigned blk = blockIdx.x;              // 256: s = blk>>4, chunk = blk&15
    unsigned s = blk >> 4, ch = blk & 15;
    unsigned m = s >> 2, b = s & 3;
    const int* ip = (m == 0) ? i0 : (m == 1) ? i1 : (m == 2) ? i2 : i3;
    unsigned base = b * 131072u + ch * 4096u;
#pragma unroll
    for (int i = 0; i < 16; ++i) {
        int r = ip[base + t + i * 256];
        atomicAdd(&lc[r], 1);
    }
    __syncthreads();
    int* cs = counts + s * 4096;
#pragma unroll
    for (int i = 0; i < 16; ++i) {
        int v = lc[t + i * 256];
        if (v) atomicAdd(cs + t + i * 256, v);
    }
}

__global__ __launch_bounds__(256) void k_scan(const int* __restrict__ counts,
                                              int* __restrict__ rowptr,
                                              int* __restrict__ cursor) {
    int s = blockIdx.x, t = threadIdx.x;
    int loc[16];
    int base = t * 16;
    const int* cs = counts + s * 4096;
    int run = 0;
#pragma unroll
    for (int i = 0; i < 16; ++i) { loc[i] = run; run += cs[base + i]; }
    int total = run;
    int lane = t & 63, wv = t >> 6;
    int v = total;
#pragma unroll
    for (int d = 1; d < 64; d <<= 1) { int u = __shfl_up(v, d, 64); if (lane >= d) v += u; }
    __shared__ int wt[4];
    if (lane == 63) wt[wv] = v;
    __syncthreads();
    int pre = v - total;
    for (int i = 0; i < wv; ++i) pre += wt[i];
    int* rp = rowptr + s * 4097;
    int* cu = cursor + s * 4096;
#pragma unroll
    for (int i = 0; i < 16; ++i) { rp[base + i] = pre + loc[i]; cu[base + i] = pre + loc[i]; }
    if (t == 255) rp[4096] = pre + total;
}

__global__ __launch_bounds__(256) void k_scatter(const int* __restrict__ i0, const int* __restrict__ i1,
                                                 const int* __restrict__ i2, const int* __restrict__ i3,
                                                 const float* __restrict__ v0, const float* __restrict__ v1,
                                                 const float* __restrict__ v2, const float* __restrict__ v3,
                                                 const float* __restrict__ d1, const float* __restrict__ d2,
                                                 int* __restrict__ cursor,
                                                 unsigned* __restrict__ ep) {
    unsigned gid = blockIdx.x * 256 + threadIdx.x;
    unsigned s = gid >> 16, e = gid & 65535;
    unsigned m = s >> 2, b = s & 3;
    const int* ip = (m == 0) ? i0 : (m == 1) ? i1 : (m == 2) ? i2 : i3;
    const float* vp = (m == 0) ? v0 : (m == 1) ? v1 : (m == 2) ? v2 : v3;
    int r = ip[(size_t)b * 131072 + e];
    int c = ip[(size_t)b * 131072 + 65536 + e];
    float v = vp[(size_t)b * 65536 + e];
    if (m == 1) v *= d1[c];
    if (m == 3) v *= d2[c];
    int pos = atomicAdd(cursor + s * 4096 + r, 1);
    ep[(size_t)s * 65536 + pos] = ((unsigned)c << 16) | (unsigned)f2bf(v);   // col|bf16(val), 4B/edge
}

// ---- pass 1: y1 = inv1@filt1, y2 = inv2@filt2 (gather, no atomics) ---------
__global__ __launch_bounds__(128) void k_gather1(const int* __restrict__ rowptr,
                                                 const unsigned* __restrict__ ep,
                                                 const unsigned short* __restrict__ filt1,
                                                 const unsigned short* __restrict__ filt2,
                                                 unsigned short* __restrict__ y1,
                                                 unsigned short* __restrict__ y2) {
    unsigned blk = blockIdx.x;                 // 32768: [mm][row][b]
    unsigned b = blk & 3, row = (blk >> 2) & 4095, mm = blk >> 14;
    int s = (mm ? 8 : 0) + (int)b;             // inv1: s=b ; inv2: s=8+b
    const unsigned short* X = mm ? filt2 : filt1;
    unsigned short* Y = mm ? y2 : y1;
    int f = threadIdx.x;
    const int* rp = rowptr + s * 4097;
    int e0 = rp[row], e1 = rp[row + 1];
    float acc = 0.f;
    for (int e = e0; e < e1; ++e) {
        unsigned p = ep[(size_t)s * 65536 + e];
        float v = bf2f((unsigned short)(p & 0xffffu));
        int c = (int)(p >> 16);
        acc += v * bf2f(X[((size_t)b * 4096 + c) * 128 + f]);
    }
    Y[((size_t)b * 4096 + row) * 128 + f] = f2bf(acc);
}

// ---- pass 2: res = phi1@(d1*y1) + phi2@(d2*y2)  (d folded at scatter) ------
__global__ __launch_bounds__(128) void k_gather2(const int* __restrict__ rowptr,
                                                 const unsigned* __restrict__ ep,
                                                 const unsigned short* __restrict__ y1,
                                                 const unsigned short* __restrict__ y2,
                                                 float* __restrict__ res) {
    unsigned blk = blockIdx.x;                 // 16384
    unsigned b = blk & 3, row = blk >> 2;
    int f = threadIdx.x;
    float acc = 0.f;
    {
        int s = 4 + (int)b;                    // phi1
        const int* rp = rowptr + s * 4097;
        int e0 = rp[row], e1 = rp[row + 1];
        for (int e = e0; e < e1; ++e) {
            unsigned p = ep[(size_t)s * 65536 + e];
            float v = bf2f((unsigned short)(p & 0xffffu));
            int c = (int)(p >> 16);
            acc += v * bf2f(y1[((size_t)b * 4096 + c) * 128 + f]);
        }
    }
    {
        int s = 12 + (int)b;                   // phi2
        const int* rp = rowptr + s * 4097;
        int e0 = rp[row], e1 = rp[row + 1];
        for (int e = e0; e < e1; ++e) {
            unsigned p = ep[(size_t)s * 65536 + e];
            float v = bf2f((unsigned short)(p & 0xffffu));
            int c = (int)(p >> 16);
            acc += v * bf2f(y2[((size_t)b * 4096 + c) * 128 + f]);
        }
    }
    res[((size_t)b * 4096 + row) * 128 + f] = acc;
}

// ---- xproj[p=l*4+b][n] = item_emb[joblst[b,l]] . W_ih[n] + b_ih[n] + b_hh[n]
__global__ __launch_bounds__(256) void k_xproj(const float* __restrict__ item_emb,
                                               const int* __restrict__ joblst,
                                               const float* __restrict__ W_ih,
                                               const float* __restrict__ b_ih,
                                               const float* __restrict__ b_hh,
                                               float* __restrict__ xp) {
    __shared__ float sx[8][128];
    int t = threadIdx.x;
    int n = blockIdx.x * 256 + t;
    int p0 = blockIdx.y * 8;
#pragma unroll
    for (int i = 0; i < 4; ++i) {
        int e2 = t + i * 256;
        int rr = e2 >> 7, c = e2 & 127;
        int p = p0 + rr;
        int b = p & 3, l = p >> 2;
        int j = joblst[b * LLC + l];
        sx[rr][c] = item_emb[(size_t)j * 128 + c];
    }
    __syncthreads();
    float acc[8];
#pragma unroll
    for (int r = 0; r < 8; ++r) acc[r] = 0.f;
    const float* wn = W_ih + (size_t)n * 128;
    for (int c = 0; c < 128; c += 4) {
        float4 w = *(const float4*)(wn + c);
#pragma unroll
        for (int r = 0; r < 8; ++r) {
            float4 xr = *(const float4*)&sx[r][c];
            acc[r] += xr.x * w.x + xr.y * w.y + xr.z * w.z + xr.w * w.w;
        }
    }
    float bias = b_ih[n] + b_hh[n];
#pragma unroll
    for (int r = 0; r < 8; ++r) xp[(size_t)(p0 + r) * NN + n] = acc[r] + bias;
}

// ---- whole RNN in ONE cooperative kernel ------------------------------------
// 256 blocks x 256 threads. Block owns 16 rows; wave wv owns rows wv*4..wv*4+3.
// W int8 (x8192) resident in VGPRs: lane holds 4 rows x 64-elem m-seg = 64 dwords.
// h int8 (x127) double-buffered in global (hq), staged to LDS each step.
// dot: v_dot4_i32_i8; reduce: DPP (VALU pipe); sync: cg::grid.sync().
__global__ __launch_bounds__(256) void k_rnn_all(const unsigned* __restrict__ w8,
                                                 const float* __restrict__ xp,
                                                 unsigned* __restrict__ hq,   // [2][4][1024]
                                                 float* __restrict__ hfin) {  // [4][4096]
    __shared__ unsigned hs[4096];              // [b][1024 dwords] = 16KB
    __shared__ int red[4][16];
    __shared__ unsigned char hpk[4][4][4];     // [wv][b][rr]
    cg::grid_group grid = cg::this_grid();
    int t = threadIdx.x;
    int lane = t & 63, wv = t >> 6;
    int row_base = blockIdx.x * 16;

    // load W fragment into registers (once)
    unsigned W[4][16];
    const unsigned* wb = w8 + (size_t)(row_base + wv * 4) * 1024 + lane * 16;
#pragma unroll
    for (int r = 0; r < 4; ++r)
#pragma unroll
        for (int k4 = 0; k4 < 4; ++k4)
            *(uint4*)&W[r][k4 * 4] = *(const uint4*)(wb + (size_t)r * 1024 + k4 * 4);

    const float SC = 1.f / (8192.f * 127.f);

    for (int l = 0; l < LLC; ++l) {
        int acc[4][4];
#pragma unroll
        for (int r = 0; r < 4; ++r)
#pragma unroll
            for (int b = 0; b < 4; ++b) acc[r][b] = 0;

        if (l > 0) {
#pragma unroll
            for (int k4 = 0; k4 < 4; ++k4) {
                uint4 h0 = *(const uint4*)&hs[0 * 1024 + lane * 16 + k4 * 4];
                uint4 h1 = *(const uint4*)&hs[1 * 1024 + lane * 16 + k4 * 4];
                uint4 h2 = *(const uint4*)&hs[2 * 1024 + lane * 16 + k4 * 4];
                uint4 h3 = *(const uint4*)&hs[3 * 1024 + lane * 16 + k4 * 4];
#pragma unroll
                for (int r = 0; r < 4; ++r) {
                    acc[r][0] = SDOT4(W[r][k4 * 4 + 0], h0.x, acc[r][0]);
                    acc[r][1] = SDOT4(W[r][k4 * 4 + 0], h1.x, acc[r][1]);
                    acc[r][2] = SDOT4(W[r][k4 * 4 + 0], h2.x, acc[r][2]);
                    acc[r][3] = SDOT4(W[r][k4 * 4 + 0], h3.x, acc[r][3]);
                    acc[r][0] = SDOT4(W[r][k4 * 4 + 1], h0.y, acc[r][0]);
                    acc[r][1] = SDOT4(W[r][k4 * 4 + 1], h1.y, acc[r][1]);
                    acc[r][2] = SDOT4(W[r][k4 * 4 + 1], h2.y, acc[r][2]);
                    acc[r][3] = SDOT4(W[r][k4 * 4 + 1], h3.y, acc[r][3]);
                    acc[r][0] = SDOT4(W[r][k4 * 4 + 2], h0.z, acc[r][0]);
                    acc[r][1] = SDOT4(W[r][k4 * 4 + 2], h1.z, acc[r][1]);
                    acc[r][2] = SDOT4(W[r][k4 * 4 + 2], h2.z, acc[r][2]);
                    acc[r][3] = SDOT4(W[r][k4 * 4 + 2], h3.z, acc[r][3]);
                    acc[r][0] = SDOT4(W[r][k4 * 4 + 3], h0.w, acc[r][0]);
                    acc[r][1] = SDOT4(W[r][k4 * 4 + 3], h1.w, acc[r][1]);
                    acc[r][2] = SDOT4(W[r][k4 * 4 + 3], h2.w, acc[r][2]);
                    acc[r][3] = SDOT4(W[r][k4 * 4 + 3], h3.w, acc[r][3]);
                }
            }
            // reduce 16 accumulators across the wave (DPP, totals in lane 63)
#pragma unroll
            for (int r = 0; r < 4; ++r)
#pragma unroll
                for (int b = 0; b < 4; ++b) acc[r][b] = wred64(acc[r][b]);
            if (lane == 63) {
#pragma unroll
                for (int b = 0; b < 4; ++b) {
                    int4 q = { acc[0][b], acc[1][b], acc[2][b], acc[3][b] };
                    *(int4*)&red[wv][b * 4] = q;   // red[wv][b*4+rr]
                }
            }
        }
        // tail: 16 lanes produce this wave's 4 rows x 4 batches
        if (lane < 16) {
            int b = lane >> 2, rr = lane & 3;
            int row = row_base + wv * 4 + rr;
            float a = (l > 0) ? (float)red[wv][lane] * SC : 0.f;
            float pre = a + xp[(size_t)(l * 4 + b) * NN + row];
            float hnew = tanhf(pre);
            if (l == LLC - 1) hfin[(size_t)b * NN + row] = hnew;
            int q = (int)rintf(hnew * 127.f);
            hpk[wv][b][rr] = (unsigned char)(q & 0xff);
        }
        if (lane < 4) {
            unsigned d = *(const unsigned*)&hpk[wv][lane][0];
            hq[(size_t)(l & 1) * 4096 + (size_t)lane * 1024 + (row_base >> 2) + wv] = d;
        }
        __threadfence();
        grid.sync();
        __threadfence();
        // refill LDS h-stage from the buffer just written
        const unsigned* src = hq + (size_t)(l & 1) * 4096;
#pragma unroll
        for (int i = 0; i < 4; ++i)
            *(uint4*)&hs[i * 1024 + t * 4] = *(const uint4*)(src + i * 1024 + t * 4);
        __syncthreads();
    }
}

// ---- out[b,n,k] = sigmoid( gelu(res.dW[k]+db) * gelu(Emb) ), LDS-staged ----
__global__ __launch_bounds__(256) void k_final(const float* __restrict__ res,
                                               const float* __restrict__ dW,
                                               const float* __restrict__ db,
                                               const float* __restrict__ hfin,
                                               float* __restrict__ out) {
    __shared__ float4 sres4[512];          // 16 rows x 128
    __shared__ float sdw[10 * 132];        // pad 132: kills bank conflict
    int t = threadIdx.x;
    int row0 = blockIdx.x * 16;
    {
        const float4* src = (const float4*)(res + (size_t)row0 * 128);
        sres4[t] = src[t];
        sres4[t + 256] = src[t + 256];
    }
    for (int i = t; i < 1280; i += 256) { int k = i >> 7, c = i & 127; sdw[k * 132 + c] = dW[i]; }
    __syncthreads();
    int r = t >> 4, k = t & 15;
    if (k < 10) {
        const float* rr = (const float*)sres4 + r * 128;
        const float* wk = sdw + k * 132;
        float acc = 0.f;
#pragma unroll
        for (int c = 0; c < 128; c += 4) {
            float4 a = *(const float4*)(rr + c);
            float4 w = *(const float4*)(wk + c);
            acc += a.x * w.x + a.y * w.y + a.z * w.z + a.w * w.w;
        }
        float pre = acc + db[k];
        int grow = row0 + r;
        int b = grow >> 12, n = grow & 4095;
        float e = hfin[(size_t)b * NN + n];
        float g1 = 0.5f * pre * (1.f + erff(pre * 0.70710678118f));
        float ge = 0.5f * e * (1.f + erff(e * 0.70710678118f));
        out[(size_t)grow * 10 + k] = 1.f / (1.f + __expf(-g1 * ge));
    }
}

extern "C" void kernel_launch(void* const* d_in, const int* in_sizes, int n_in,
                              void* d_out, int out_size, void* d_ws, size_t ws_size,
                              hipStream_t stream) {
    const int*   phi1_idx = (const int*)d_in[0];
    const float* phi1_val = (const float*)d_in[1];
    const int*   inv1_idx = (const int*)d_in[2];
    const float* inv1_val = (const float*)d_in[3];
    const int*   phi2_idx = (const int*)d_in[4];
    const float* phi2_val = (const float*)d_in[5];
    const int*   inv2_idx = (const int*)d_in[6];
    const float* inv2_val = (const float*)d_in[7];
    const float* fea      = (const float*)d_in[8];
    const int*   joblst   = (const int*)d_in[9];
    const float* W1       = (const float*)d_in[10];
    const float* d1       = (const float*)d_in[11];
    const float* W2       = (const float*)d_in[12];
    const float* d2       = (const float*)d_in[13];
    const float* W_ih     = (const float*)d_in[14];
    const float* W_hh     = (const float*)d_in[15];
    const float* b_ih     = (const float*)d_in[16];
    const float* b_hh     = (const float*)d_in[17];
    const float* dense_W  = (const float*)d_in[18];
    const float* dense_b  = (const float*)d_in[19];
    const float* item_emb = (const float*)d_in[20];

    float* ws = (float*)d_ws;                       // slot = 4B
    unsigned short* filt1 = (unsigned short*)ws;            // 1,048,576 slots
    unsigned short* filt2 = (unsigned short*)(ws + 1048576);
    unsigned short* y1    = (unsigned short*)(ws + 2097152);
    unsigned short* y2    = (unsigned short*)(ws + 3145728);
    float* res  = ws + 4194304;                     // 2,097,152 slots
    float* xp   = ws + 6291456;                     // 819,200
    float* hfin = ws + 7110656;                     // 16,384
    unsigned* hq  = (unsigned*)(ws + 7127040);      // 8,192 (2 x 4 x 1024 dwords)
    unsigned* w8u = (unsigned*)(ws + 7135232);      // 4,194,304 slots (16MB int8)
    int*   counts = (int*)(ws + 11329536);          // 65,536
    int*   rowptr = (int*)(ws + 11395072);          // 65,552
    int*   cursor = (int*)(ws + 11460624);          // 65,536
    unsigned* ep  = (unsigned*)(ws + 11526160);     // 1,048,576 (packed col|val)

    hipMemsetAsync(counts, 0, 16 * 4096 * sizeof(int), stream);

    k_w8<<<16384, 256, 0, stream>>>(W_hh, w8u);
    k_filt<<<1024, 128, 0, stream>>>(fea, W1, W2, filt1, filt2);
    k_xproj<<<dim3(16, 25), 256, 0, stream>>>(item_emb, joblst, W_ih, b_ih, b_hh, xp);

    k_hist<<<256, 256, 0, stream>>>(inv1_idx, phi1_idx, inv2_idx, phi2_idx, counts);
    k_scan<<<16, 256, 0, stream>>>(counts, rowptr, cursor);
    k_scatter<<<4096, 256, 0, stream>>>(inv1_idx, phi1_idx, inv2_idx, phi2_idx,
                                        inv1_val, phi1_val, inv2_val, phi2_val,
                                        d1, d2, cursor, ep);

    k_gather1<<<32768, 128, 0, stream>>>(rowptr, ep, filt1, filt2, y1, y2);
    k_gather2<<<16384, 128, 0, stream>>>(rowptr, ep, y1, y2, res);

    {   // whole RNN: one cooperative launch, grid.sync between steps
        void* args[] = { (void*)&w8u, (void*)&xp, (void*)&hq, (void*)&hfin };
        hipLaunchCooperativeKernel((const void*)k_rnn_all, dim3(256), dim3(256),
                                   args, 0, stream);
    }

    k_final<<<1024, 256, 0, stream>>>(res, dense_W, dense_b, hfin, (float*)d_out);
}

// Round 4
// 551.760 us; speedup vs baseline: 6.6041x; 6.6041x over previous
//
#include <hip/hip_runtime.h>
#include <cstdint>
#include <cstddef>

#define NN   4096
#define LLC  50

__device__ __forceinline__ float bf2f(unsigned short u) {
    return __uint_as_float(((unsigned)u) << 16);
}
__device__ __forceinline__ unsigned short f2bf(float x) {
    unsigned b = __float_as_uint(x);
    return (unsigned short)((b + 0x7fffu + ((b >> 16) & 1u)) >> 16);
}

#if __has_builtin(__builtin_amdgcn_sdot4)
#define SDOT4(a, b, c) __builtin_amdgcn_sdot4((int)(a), (int)(b), (c), false)
#else
__device__ __forceinline__ int sdot4_sw(unsigned a, unsigned b, int c) {
    c += (int)(signed char)(a) * (int)(signed char)(b);
    c += (int)(signed char)(a >> 8) * (int)(signed char)(b >> 8);
    c += (int)(signed char)(a >> 16) * (int)(signed char)(b >> 16);
    c += (int)(signed char)(a >> 24) * (int)(signed char)(b >> 24);
    return c;
}
#define SDOT4(a, b, c) sdot4_sw((a), (b), (c))
#endif

// sum across 64 lanes via DPP (VALU pipe); total lands in lane 63
#define DPPADD(v, ctrl, rmask) \
    ((v) + __builtin_amdgcn_update_dpp(0, (v), (ctrl), (rmask), 0xf, true))
__device__ __forceinline__ int wred64(int v) {
    v = DPPADD(v, 0x111, 0xf);   // row_shr:1
    v = DPPADD(v, 0x112, 0xf);   // row_shr:2
    v = DPPADD(v, 0x114, 0xf);   // row_shr:4
    v = DPPADD(v, 0x118, 0xf);   // row_shr:8
    v = DPPADD(v, 0x142, 0xa);   // row_bcast15
    v = DPPADD(v, 0x143, 0xc);   // row_bcast31 -> lane63=total
    return v;
}

// ---- W_hh fp32 -> int8 (x8192), REPACKED for lane-contiguous rnn loads -----
// Wp dword index p = row*1024 + k4*256 + lane*4 + i  holds input k-dword
// k = lane*16 + k4*4 + i (cols 4k..4k+3 of `row`). Each thread emits one uint4.
__global__ __launch_bounds__(256) void k_w8(const float* __restrict__ W,
                                            uint4* __restrict__ out) {
    unsigned T = blockIdx.x * 256 + threadIdx.x;     // [0, 1M)
    unsigned row = T >> 8, rem = T & 255;
    unsigned k4 = rem >> 6, lane = rem & 63;
    unsigned k0 = lane * 16 + k4 * 4;                // first input dword
    const float* src = W + ((size_t)row * 1024 + k0) * 4;  // 16 consecutive floats
    unsigned q[4];
#pragma unroll
    for (int i = 0; i < 4; ++i) {
        float4 w = *(const float4*)(src + i * 4);
        int q0 = (int)rintf(fminf(fmaxf(w.x * 8192.f, -127.f), 127.f));
        int q1 = (int)rintf(fminf(fmaxf(w.y * 8192.f, -127.f), 127.f));
        int q2 = (int)rintf(fminf(fmaxf(w.z * 8192.f, -127.f), 127.f));
        int q3 = (int)rintf(fminf(fmaxf(w.w * 8192.f, -127.f), 127.f));
        q[i] = (q0 & 0xff) | ((q1 & 0xff) << 8) | ((q2 & 0xff) << 16) | ((q3 & 0xff) << 24);
    }
    out[(size_t)row * 256 + k4 * 64 + lane] = make_uint4(q[0], q[1], q[2], q[3]);
}

// ---- filt1 = fea@W1, filt2 = fea@W2  -> bf16 [16384,128] -------------------
__global__ __launch_bounds__(128) void k_filt(const float* __restrict__ fea,
                                              const float* __restrict__ W1,
                                              const float* __restrict__ W2,
                                              unsigned short* __restrict__ f1,
                                              unsigned short* __restrict__ f2) {
    __shared__ float sfea[16][128];
    int t = threadIdx.x;
    int rb = blockIdx.x * 16;
    for (int r = 0; r < 16; ++r) sfea[r][t] = fea[(size_t)(rb + r) * 128 + t];
    __syncthreads();
    float a1[16], a2[16];
#pragma unroll
    for (int r = 0; r < 16; ++r) { a1[r] = 0.f; a2[r] = 0.f; }
    for (int c = 0; c < 128; c += 4) {
        float w10 = W1[(c + 0) * 128 + t], w11 = W1[(c + 1) * 128 + t];
        float w12 = W1[(c + 2) * 128 + t], w13 = W1[(c + 3) * 128 + t];
        float w20 = W2[(c + 0) * 128 + t], w21 = W2[(c + 1) * 128 + t];
        float w22 = W2[(c + 2) * 128 + t], w23 = W2[(c + 3) * 128 + t];
#pragma unroll
        for (int r = 0; r < 16; ++r) {
            float4 f = *(const float4*)&sfea[r][c];
            a1[r] += f.x * w10 + f.y * w11 + f.z * w12 + f.w * w13;
            a2[r] += f.x * w20 + f.y * w21 + f.z * w22 + f.w * w23;
        }
    }
#pragma unroll
    for (int r = 0; r < 16; ++r) {
        f1[(size_t)(rb + r) * 128 + t] = f2bf(a1[r]);
        f2[(size_t)(rb + r) * 128 + t] = f2bf(a2[r]);
    }
}

// ---- CSR build: LDS-privatized histogram -> scan -> packed scatter ----------
__global__ __launch_bounds__(256) void k_hist(const int* __restrict__ i0, const int* __restrict__ i1,
                                              const int* __restrict__ i2, const int* __restrict__ i3,
                                              int* __restrict__ counts) {
    __shared__ int lc[4096];
    int t = threadIdx.x;
#pragma unroll
    for (int i = 0; i < 16; ++i) lc[t + i * 256] = 0;
    __syncthreads();
    unsigned blk = blockIdx.x;              // 256: s = blk>>4, chunk = blk&15
    unsigned s = blk >> 4, ch = blk & 15;
    unsigned m = s >> 2, b = s & 3;
    const int* ip = (m == 0) ? i0 : (m == 1) ? i1 : (m == 2) ? i2 : i3;
    unsigned base = b * 131072u + ch * 4096u;
#pragma unroll
    for (int i = 0; i < 16; ++i) {
        int r = ip[base + t + i * 256];
        atomicAdd(&lc[r], 1);
    }
    __syncthreads();
    int* cs = counts + s * 4096;
#pragma unroll
    for (int i = 0; i < 16; ++i) {
        int v = lc[t + i * 256];
        if (v) atomicAdd(cs + t + i * 256, v);
    }
}

__global__ __launch_bounds__(256) void k_scan(const int* __restrict__ counts,
                                              int* __restrict__ rowptr,
                                              int* __restrict__ cursor) {
    int s = blockIdx.x, t = threadIdx.x;
    int loc[16];
    int base = t * 16;
    const int* cs = counts + s * 4096;
    int run = 0;
#pragma unroll
    for (int i = 0; i < 16; ++i) { loc[i] = run; run += cs[base + i]; }
    int total = run;
    int lane = t & 63, wv = t >> 6;
    int v = total;
#pragma unroll
    for (int d = 1; d < 64; d <<= 1) { int u = __shfl_up(v, d, 64); if (lane >= d) v += u; }
    __shared__ int wt[4];
    if (lane == 63) wt[wv] = v;
    __syncthreads();
    int pre = v - total;
    for (int i = 0; i < wv; ++i) pre += wt[i];
    int* rp = rowptr + s * 4097;
    int* cu = cursor + s * 4096;
#pragma unroll
    for (int i = 0; i < 16; ++i) { rp[base + i] = pre + loc[i]; cu[base + i] = pre + loc[i]; }
    if (t == 255) rp[4096] = pre + total;
}

__global__ __launch_bounds__(256) void k_scatter(const int* __restrict__ i0, const int* __restrict__ i1,
                                                 const int* __restrict__ i2, const int* __restrict__ i3,
                                                 const float* __restrict__ v0, const float* __restrict__ v1,
                                                 const float* __restrict__ v2, const float* __restrict__ v3,
                                                 const float* __restrict__ d1, const float* __restrict__ d2,
                                                 int* __restrict__ cursor,
                                                 unsigned* __restrict__ ep) {
    unsigned gid = blockIdx.x * 256 + threadIdx.x;
    unsigned s = gid >> 16, e = gid & 65535;
    unsigned m = s >> 2, b = s & 3;
    const int* ip = (m == 0) ? i0 : (m == 1) ? i1 : (m == 2) ? i2 : i3;
    const float* vp = (m == 0) ? v0 : (m == 1) ? v1 : (m == 2) ? v2 : v3;
    int r = ip[(size_t)b * 131072 + e];
    int c = ip[(size_t)b * 131072 + 65536 + e];
    float v = vp[(size_t)b * 65536 + e];
    if (m == 1) v *= d1[c];
    if (m == 3) v *= d2[c];
    int pos = atomicAdd(cursor + s * 4096 + r, 1);
    ep[(size_t)s * 65536 + pos] = ((unsigned)c << 16) | (unsigned)f2bf(v);   // col|bf16(val)
}

// ---- pass 1: y1 = inv1@filt1, y2 = inv2@filt2 (gather, no atomics) ---------
__global__ __launch_bounds__(128) void k_gather1(const int* __restrict__ rowptr,
                                                 const unsigned* __restrict__ ep,
                                                 const unsigned short* __restrict__ filt1,
                                                 const unsigned short* __restrict__ filt2,
                                                 unsigned short* __restrict__ y1,
                                                 unsigned short* __restrict__ y2) {
    unsigned blk = blockIdx.x;                 // 32768: [mm][row][b]
    unsigned b = blk & 3, row = (blk >> 2) & 4095, mm = blk >> 14;
    int s = (mm ? 8 : 0) + (int)b;
    const unsigned short* X = mm ? filt2 : filt1;
    unsigned short* Y = mm ? y2 : y1;
    int f = threadIdx.x;
    const int* rp = rowptr + s * 4097;
    int e0 = rp[row], e1 = rp[row + 1];
    float acc = 0.f;
    for (int e = e0; e < e1; ++e) {
        unsigned p = ep[(size_t)s * 65536 + e];
        float v = bf2f((unsigned short)(p & 0xffffu));
        int c = (int)(p >> 16);
        acc += v * bf2f(X[((size_t)b * 4096 + c) * 128 + f]);
    }
    Y[((size_t)b * 4096 + row) * 128 + f] = f2bf(acc);
}

// ---- pass 2: res = phi1@(d1*y1) + phi2@(d2*y2) -----------------------------
__global__ __launch_bounds__(128) void k_gather2(const int* __restrict__ rowptr,
                                                 const unsigned* __restrict__ ep,
                                                 const unsigned short* __restrict__ y1,
                                                 const unsigned short* __restrict__ y2,
                                                 float* __restrict__ res) {
    unsigned blk = blockIdx.x;                 // 16384
    unsigned b = blk & 3, row = blk >> 2;
    int f = threadIdx.x;
    float acc = 0.f;
    {
        int s = 4 + (int)b;
        const int* rp = rowptr + s * 4097;
        int e0 = rp[row], e1 = rp[row + 1];
        for (int e = e0; e < e1; ++e) {
            unsigned p = ep[(size_t)s * 65536 + e];
            float v = bf2f((unsigned short)(p & 0xffffu));
            int c = (int)(p >> 16);
            acc += v * bf2f(y1[((size_t)b * 4096 + c) * 128 + f]);
        }
    }
    {
        int s = 12 + (int)b;
        const int* rp = rowptr + s * 4097;
        int e0 = rp[row], e1 = rp[row + 1];
        for (int e = e0; e < e1; ++e) {
            unsigned p = ep[(size_t)s * 65536 + e];
            float v = bf2f((unsigned short)(p & 0xffffu));
            int c = (int)(p >> 16);
            acc += v * bf2f(y2[((size_t)b * 4096 + c) * 128 + f]);
        }
    }
    res[((size_t)b * 4096 + row) * 128 + f] = acc;
}

// ---- xproj[p=l*4+b][n] --------------------------------------------------------
__global__ __launch_bounds__(256) void k_xproj(const float* __restrict__ item_emb,
                                               const int* __restrict__ joblst,
                                               const float* __restrict__ W_ih,
                                               const float* __restrict__ b_ih,
                                               const float* __restrict__ b_hh,
                                               float* __restrict__ xp) {
    __shared__ float sx[8][128];
    int t = threadIdx.x;
    int n = blockIdx.x * 256 + t;
    int p0 = blockIdx.y * 8;
#pragma unroll
    for (int i = 0; i < 4; ++i) {
        int e2 = t + i * 256;
        int rr = e2 >> 7, c = e2 & 127;
        int p = p0 + rr;
        int b = p & 3, l = p >> 2;
        int j = joblst[b * LLC + l];
        sx[rr][c] = item_emb[(size_t)j * 128 + c];
    }
    __syncthreads();
    float acc[8];
#pragma unroll
    for (int r = 0; r < 8; ++r) acc[r] = 0.f;
    const float* wn = W_ih + (size_t)n * 128;
    for (int c = 0; c < 128; c += 4) {
        float4 w = *(const float4*)(wn + c);
#pragma unroll
        for (int r = 0; r < 8; ++r) {
            float4 xr = *(const float4*)&sx[r][c];
            acc[r] += xr.x * w.x + xr.y * w.y + xr.z * w.z + xr.w * w.w;
        }
    }
    float bias = b_ih[n] + b_hh[n];
#pragma unroll
    for (int r = 0; r < 8; ++r) xp[(size_t)(p0 + r) * NN + n] = acc[r] + bias;
}

// ---- step 0: hq[0] = quant(tanh(xp[l=0]))  (h0 = 0) ------------------------
// hq dword layout: [b][rowd]  (rowd = row>>2, bytes = rows 4rowd..4rowd+3)
__global__ __launch_bounds__(256) void k_rnn_first(const float* __restrict__ xp,
                                                   unsigned* __restrict__ hq0) {
    unsigned D = blockIdx.x * 256 + threadIdx.x;   // [0,4096)
    unsigned b = D >> 10, rowd = D & 1023;
    unsigned d = 0;
#pragma unroll
    for (int i = 0; i < 4; ++i) {
        float h = tanhf(xp[(size_t)b * NN + rowd * 4 + i]);
        int q = (int)rintf(h * 127.f);
        d |= ((unsigned)(q & 0xff)) << (8 * i);
    }
    hq0[D] = d;
}

// ---- one RNN step: int8 W (repacked, L2-resident) x int8 h (16KB, L1-hot) --
// 256 blocks x 256 thr; wave wv owns rows wrow..wrow+3; lane covers k-dwords
// lane*16..lane*16+15. No LDS staging, no barriers in the hot path.
__global__ __launch_bounds__(256) void k_rnn_step(const uint4* __restrict__ Wp,
                                                  const float* __restrict__ xp,
                                                  const unsigned* __restrict__ hin,
                                                  unsigned* __restrict__ hout,
                                                  float* __restrict__ hfin, int l) {
    __shared__ int red[4][16];
    __shared__ unsigned char hpk[4][4][4];     // [wv][b][rr]
    int t = threadIdx.x;
    int lane = t & 63, wv = t >> 6;
    int blk = blockIdx.x;
    int row_base = ((blk & 7) * 32 + (blk >> 3)) * 16;   // XCD-sliced: 512-row/XCD
    int wrow = row_base + wv * 4;

    // preload h fragment: 16 x dwordx4 (same 16KB for every block -> L1/L2 hot)
    uint4 H[4][4];
#pragma unroll
    for (int b = 0; b < 4; ++b)
#pragma unroll
        for (int k4 = 0; k4 < 4; ++k4)
            H[b][k4] = *(const uint4*)(hin + (size_t)b * 1024 + lane * 16 + k4 * 4);

    // preload W fragment: 16 x dwordx4, lane-contiguous (coalesced 4KB/wave-op)
    uint4 W[4][4];
#pragma unroll
    for (int r = 0; r < 4; ++r)
#pragma unroll
        for (int k4 = 0; k4 < 4; ++k4)
            W[r][k4] = Wp[(size_t)(wrow + r) * 256 + k4 * 64 + lane];

    int acc[4][4];
#pragma unroll
    for (int r = 0; r < 4; ++r)
#pragma unroll
        for (int b = 0; b < 4; ++b) acc[r][b] = 0;

#pragma unroll
    for (int k4 = 0; k4 < 4; ++k4)
#pragma unroll
        for (int r = 0; r < 4; ++r)
#pragma unroll
            for (int b = 0; b < 4; ++b) {
                acc[r][b] = SDOT4(W[r][k4].x, H[b][k4].x, acc[r][b]);
                acc[r][b] = SDOT4(W[r][k4].y, H[b][k4].y, acc[r][b]);
                acc[r][b] = SDOT4(W[r][k4].z, H[b][k4].z, acc[r][b]);
                acc[r][b] = SDOT4(W[r][k4].w, H[b][k4].w, acc[r][b]);
            }

#pragma unroll
    for (int r = 0; r < 4; ++r)
#pragma unroll
        for (int b = 0; b < 4; ++b) acc[r][b] = wred64(acc[r][b]);
    if (lane == 63) {
#pragma unroll
        for (int b = 0; b < 4; ++b) {
            int4 q = { acc[0][b], acc[1][b], acc[2][b], acc[3][b] };
            *(int4*)&red[wv][b * 4] = q;       // red[wv][b*4+rr]
        }
    }
    // same-wave LDS dependency: no barrier needed
    if (lane < 16) {
        const float SC = 1.f / (8192.f * 127.f);
        int b = lane >> 2, rr = lane & 3;
        int row = wrow + rr;
        float pre = (float)red[wv][lane] * SC + xp[(size_t)(l * 4 + b) * NN + row];
        float hnew = tanhf(pre);
        if (l == LLC - 1) hfin[(size_t)b * NN + row] = hnew;
        int q = (int)rintf(hnew * 127.f);
        hpk[wv][b][rr] = (unsigned char)(q & 0xff);
    }
    if (lane < 4) {
        unsigned d = *(const unsigned*)&hpk[wv][lane][0];
        hout[(size_t)lane * 1024 + (row_base >> 2) + wv] = d;
    }
}

// ---- out[b,n,k] = sigmoid( gelu(res.dW[k]+db) * gelu(Emb) ), LDS-staged ----
__global__ __launch_bounds__(256) void k_final(const float* __restrict__ res,
                                               const float* __restrict__ dW,
                                               const float* __restrict__ db,
                                               const float* __restrict__ hfin,
                                               float* __restrict__ out) {
    __shared__ float4 sres4[512];          // 16 rows x 128
    __shared__ float sdw[10 * 132];        // pad 132: kills bank conflict
    int t = threadIdx.x;
    int row0 = blockIdx.x * 16;
    {
        const float4* src = (const float4*)(res + (size_t)row0 * 128);
        sres4[t] = src[t];
        sres4[t + 256] = src[t + 256];
    }
    for (int i = t; i < 1280; i += 256) { int k = i >> 7, c = i & 127; sdw[k * 132 + c] = dW[i]; }
    __syncthreads();
    int r = t >> 4, k = t & 15;
    if (k < 10) {
        const float* rr = (const float*)sres4 + r * 128;
        const float* wk = sdw + k * 132;
        float acc = 0.f;
#pragma unroll
        for (int c = 0; c < 128; c += 4) {
            float4 a = *(const float4*)(rr + c);
            float4 w = *(const float4*)(wk + c);
            acc += a.x * w.x + a.y * w.y + a.z * w.z + a.w * w.w;
        }
        float pre = acc + db[k];
        int grow = row0 + r;
        int b = grow >> 12, n = grow & 4095;
        float e = hfin[(size_t)b * NN + n];
        float g1 = 0.5f * pre * (1.f + erff(pre * 0.70710678118f));
        float ge = 0.5f * e * (1.f + erff(e * 0.70710678118f));
        out[(size_t)grow * 10 + k] = 1.f / (1.f + __expf(-g1 * ge));
    }
}

extern "C" void kernel_launch(void* const* d_in, const int* in_sizes, int n_in,
                              void* d_out, int out_size, void* d_ws, size_t ws_size,
                              hipStream_t stream) {
    const int*   phi1_idx = (const int*)d_in[0];
    const float* phi1_val = (const float*)d_in[1];
    const int*   inv1_idx = (const int*)d_in[2];
    const float* inv1_val = (const float*)d_in[3];
    const int*   phi2_idx = (const int*)d_in[4];
    const float* phi2_val = (const float*)d_in[5];
    const int*   inv2_idx = (const int*)d_in[6];
    const float* inv2_val = (const float*)d_in[7];
    const float* fea      = (const float*)d_in[8];
    const int*   joblst   = (const int*)d_in[9];
    const float* W1       = (const float*)d_in[10];
    const float* d1       = (const float*)d_in[11];
    const float* W2       = (const float*)d_in[12];
    const float* d2       = (const float*)d_in[13];
    const float* W_ih     = (const float*)d_in[14];
    const float* W_hh     = (const float*)d_in[15];
    const float* b_ih     = (const float*)d_in[16];
    const float* b_hh     = (const float*)d_in[17];
    const float* dense_W  = (const float*)d_in[18];
    const float* dense_b  = (const float*)d_in[19];
    const float* item_emb = (const float*)d_in[20];

    float* ws = (float*)d_ws;                       // slot = 4B
    unsigned short* filt1 = (unsigned short*)ws;            // 1,048,576 slots
    unsigned short* filt2 = (unsigned short*)(ws + 1048576);
    unsigned short* y1    = (unsigned short*)(ws + 2097152);
    unsigned short* y2    = (unsigned short*)(ws + 3145728);
    float* res  = ws + 4194304;                     // 2,097,152 slots
    float* xp   = ws + 6291456;                     // 819,200
    float* hfin = ws + 7110656;                     // 16,384
    unsigned* hq  = (unsigned*)(ws + 7127040);      // 8,192 (2 x 4 x 1024 dwords)
    uint4* w8p = (uint4*)(ws + 7135232);            // 16MB repacked int8 W
    int*   counts = (int*)(ws + 11329536);          // 65,536
    int*   rowptr = (int*)(ws + 11395072);          // 65,552
    int*   cursor = (int*)(ws + 11460624);          // 65,536
    unsigned* ep  = (unsigned*)(ws + 11526160);     // 1,048,576 (packed col|val)

    hipMemsetAsync(counts, 0, 16 * 4096 * sizeof(int), stream);

    k_w8<<<4096, 256, 0, stream>>>(W_hh, w8p);
    k_filt<<<1024, 128, 0, stream>>>(fea, W1, W2, filt1, filt2);
    k_xproj<<<dim3(16, 25), 256, 0, stream>>>(item_emb, joblst, W_ih, b_ih, b_hh, xp);

    k_hist<<<256, 256, 0, stream>>>(inv1_idx, phi1_idx, inv2_idx, phi2_idx, counts);
    k_scan<<<16, 256, 0, stream>>>(counts, rowptr, cursor);
    k_scatter<<<4096, 256, 0, stream>>>(inv1_idx, phi1_idx, inv2_idx, phi2_idx,
                                        inv1_val, phi1_val, inv2_val, phi2_val,
                                        d1, d2, cursor, ep);

    k_gather1<<<32768, 128, 0, stream>>>(rowptr, ep, filt1, filt2, y1, y2);
    k_gather2<<<16384, 128, 0, stream>>>(rowptr, ep, y1, y2, res);

    k_rnn_first<<<16, 256, 0, stream>>>(xp, hq);    // writes half 0
    for (int l = 1; l < LLC; ++l) {
        const unsigned* hin = hq + (size_t)((l - 1) & 1) * 4096;
        unsigned*       hout = hq + (size_t)(l & 1) * 4096;
        k_rnn_step<<<256, 256, 0, stream>>>(w8p, xp, hin, hout, hfin, l);
    }
    k_final<<<1024, 256, 0, stream>>>(res, dense_W, dense_b, hfin, (float*)d_out);
}